// Round 1
// baseline (4477.881 us; speedup 1.0000x reference)
//
#include <hip/hip_runtime.h>
#include <stdint.h>

typedef unsigned short u16;
typedef unsigned int   u32;

// Problem constants
constexpr int NB   = 8;      // batch
constexpr int NS   = 256;    // seq
constexpr int ND   = 1024;   // input dim
constexpr int NU   = 1024;   // hidden dim
constexpr int NE   = 4;      // experts
constexpr int MTOK = NB * NS;  // 2048 token rows

typedef float f32x4 __attribute__((ext_vector_type(4)));
typedef short bfrag __attribute__((ext_vector_type(8)));   // 8 bf16 = 4 VGPRs (guide §3)

__device__ __forceinline__ u16 f2bf(float f) {
    u32 u = __builtin_bit_cast(u32, f);
    u32 r = (u + 0x7FFFu + ((u >> 16) & 1u)) >> 16;   // RNE
    return (u16)r;
}
__device__ __forceinline__ float bf2f(u16 h) { return __builtin_bit_cast(float, (u32)h << 16); }
__device__ __forceinline__ float bflo(u32 p) { return __builtin_bit_cast(float, p << 16); }
__device__ __forceinline__ float bfhi(u32 p) { return __builtin_bit_cast(float, p & 0xFFFF0000u); }
__device__ __forceinline__ u32 pack2(float a, float b) { return (u32)f2bf(a) | ((u32)f2bf(b) << 16); }
__device__ __forceinline__ float sigm(float x) { return 1.f / (1.f + __expf(-x)); }

// ---------------- fp32 -> bf16 conversion (weights / x) ----------------
__global__ __launch_bounds__(256) void cvt_f32_bf16(const float* __restrict__ src,
                                                    u16* __restrict__ dst, int n) {
    int i = (blockIdx.x * 256 + threadIdx.x) * 8;
    if (i >= n) return;
    float4 a = *(const float4*)(src + i);
    float4 b = *(const float4*)(src + i + 4);
    uint4 o;
    o.x = pack2(a.x, a.y); o.y = pack2(a.z, a.w);
    o.z = pack2(b.x, b.y); o.w = pack2(b.z, b.w);
    *(uint4*)(dst + i) = o;
}

// ---------------- router: mean-pool + gates ----------------
__global__ __launch_bounds__(256) void pool_kernel(const float* __restrict__ x, float* __restrict__ xm) {
    int b = blockIdx.x >> 2;
    int d = (blockIdx.x & 3) * 256 + threadIdx.x;
    const float* xp = x + (size_t)b * NS * ND + d;
    float s = 0.f;
    for (int j = 0; j < NS; j++) s += xp[(size_t)j * ND];
    xm[b * ND + d] = s * (1.f / NS);
}

__global__ __launch_bounds__(256) void gates_kernel(const float* __restrict__ xm,
                                                    const float* __restrict__ rw,
                                                    const float* __restrict__ rb,
                                                    float* __restrict__ gates) {
    int b = blockIdx.x;
    int t = threadIdx.x;
    int e = t >> 6, lane = t & 63;
    float s = 0.f;
    for (int k = lane; k < ND; k += 64) s += xm[b * ND + k] * rw[e * ND + k];
    for (int o = 32; o; o >>= 1) s += __shfl_down(s, o);
    __shared__ float lg[NE];
    if (lane == 0) lg[e] = s + rb[e];
    __syncthreads();
    if (t == 0) {
        float m = fmaxf(fmaxf(lg[0], lg[1]), fmaxf(lg[2], lg[3]));
        float ex[NE]; float sum = 0.f;
        for (int i = 0; i < NE; i++) { ex[i] = __expf(lg[i] - m); sum += ex[i]; }
        for (int i = 0; i < NE; i++) gates[b * NE + i] = ex[i] / sum;
    }
}

// ---------------- GEMM: out = act(A[M,K] @ W[N,K]^T + bias) ----------------
// MODE 0: bf16, none | 1: bf16 relu | 2: bf16 sigmoid | 3: bf16 tanh*mul | 4: bf16 xz layout, bias1+bias2
template<int MODE>
__global__ __launch_bounds__(256, 2) void gemm_bt(
    const u16* __restrict__ A, int aPerExpert,
    const u16* __restrict__ Wt,
    const float* __restrict__ bias, const float* __restrict__ bias2,
    const u16* __restrict__ mul, u16* __restrict__ outp,
    int N, int K)
{
    const int e  = blockIdx.z;
    const int n0 = blockIdx.x * 64;
    const int m0 = blockIdx.y * 64;
    const int t  = threadIdx.x;
    const int wave = t >> 6, lane = t & 63;
    const int quad = lane >> 4, l16 = lane & 15;
    const int wm = (wave >> 1) * 32, wn = (wave & 1) * 32;

    __shared__ u16 As[64][40];   // +8 bf16 pad -> 2-way LDS aliasing (free, m136)
    __shared__ u16 Bs[64][40];

    const int sRow = t >> 2, sCol = (t & 3) * 8;
    const u16* aBase = A + (aPerExpert ? ((size_t)e * MTOK * K) : 0)
                         + (size_t)(m0 + sRow) * K + sCol;
    const u16* wBase = Wt + (size_t)e * N * K + (size_t)(n0 + sRow) * K + sCol;

    f32x4 acc00 = {}, acc01 = {}, acc10 = {}, acc11 = {};

    for (int k0 = 0; k0 < K; k0 += 32) {
        uint4 av = *(const uint4*)(aBase + k0);   // prefetch before barrier
        uint4 wv = *(const uint4*)(wBase + k0);
        if (k0) __syncthreads();
        *(uint4*)&As[sRow][sCol] = av;
        *(uint4*)&Bs[sRow][sCol] = wv;
        __syncthreads();
        bfrag a0 = *(const bfrag*)&As[wm + l16][quad * 8];
        bfrag a1 = *(const bfrag*)&As[wm + 16 + l16][quad * 8];
        bfrag b0 = *(const bfrag*)&Bs[wn + l16][quad * 8];
        bfrag b1 = *(const bfrag*)&Bs[wn + 16 + l16][quad * 8];
        acc00 = __builtin_amdgcn_mfma_f32_16x16x32_bf16(a0, b0, acc00, 0, 0, 0);
        acc01 = __builtin_amdgcn_mfma_f32_16x16x32_bf16(a0, b1, acc01, 0, 0, 0);
        acc10 = __builtin_amdgcn_mfma_f32_16x16x32_bf16(a1, b0, acc10, 0, 0, 0);
        acc11 = __builtin_amdgcn_mfma_f32_16x16x32_bf16(a1, b1, acc11, 0, 0, 0);
    }

    f32x4 accs[2][2] = {{acc00, acc01}, {acc10, acc11}};
    #pragma unroll
    for (int ti = 0; ti < 2; ti++) {
        #pragma unroll
        for (int tj = 0; tj < 2; tj++) {
            const int gcol = n0 + wn + tj * 16 + l16;      // C/D col = lane&15
            float bv = bias ? bias[e * N + gcol] : 0.f;
            if (MODE == 4) bv += bias2[e * N + gcol];
            #pragma unroll
            for (int r = 0; r < 4; r++) {
                const int grow = m0 + wm + ti * 16 + quad * 4 + r;   // C/D row = quad*4+reg
                float v = accs[ti][tj][r] + bv;
                if (MODE == 1) v = fmaxf(v, 0.f);
                if (MODE == 2) v = 1.f / (1.f + __expf(-v));
                size_t idx;
                if (MODE == 4) {
                    // xz layout: [e][s][b][N]; token row grow = b*256+s
                    idx = ((((size_t)e * NS + (grow & 255)) * NB + (grow >> 8)) * (size_t)N) + gcol;
                } else {
                    idx = ((size_t)e * MTOK + grow) * (size_t)N + gcol;
                }
                if (MODE == 3) v = tanhf(v) * bf2f(mul[idx]);
                outp[idx] = f2bf(v);
            }
        }
    }
}

// ---------------- LayerNorm over last dim (1024), bf16 in/out ----------------
__global__ __launch_bounds__(256) void ln_kernel(const u16* __restrict__ xin,
                                                 const float* __restrict__ gam,
                                                 const float* __restrict__ bet,
                                                 u16* __restrict__ outp) {
    const int row = blockIdx.x;          // E*MTOK rows
    const int e = row >> 11;
    const int t = threadIdx.x;
    const int wave = t >> 6, lane = t & 63;
    uint2 u = *(const uint2*)(xin + (size_t)row * NU + t * 4);
    float v0 = bflo(u.x), v1 = bfhi(u.x), v2 = bflo(u.y), v3 = bfhi(u.y);
    float s1 = v0 + v1 + v2 + v3;
    float s2 = v0*v0 + v1*v1 + v2*v2 + v3*v3;
    for (int o = 32; o; o >>= 1) { s1 += __shfl_down(s1, o); s2 += __shfl_down(s2, o); }
    __shared__ float rb[4][2];
    if (lane == 0) { rb[wave][0] = s1; rb[wave][1] = s2; }
    __syncthreads();
    s1 = rb[0][0] + rb[1][0] + rb[2][0] + rb[3][0];
    s2 = rb[0][1] + rb[1][1] + rb[2][1] + rb[3][1];
    const float mu = s1 * (1.f / NU);
    const float rstd = rsqrtf(s2 * (1.f / NU) - mu * mu + 1e-5f);
    const float* gp = gam + e * NU + t * 4;
    const float* bp = bet + e * NU + t * 4;
    uint2 o;
    o.x = pack2((v0 - mu) * rstd * gp[0] + bp[0], (v1 - mu) * rstd * gp[1] + bp[1]);
    o.y = pack2((v2 - mu) * rstd * gp[2] + bp[2], (v3 - mu) * rstd * gp[3] + bp[3]);
    *(uint2*)(outp + (size_t)row * NU + t * 4) = o;
}

// ---------------- attention: one WG per (e,b,h); thread = query row ----------------
__global__ __launch_bounds__(256, 2) void attn_kernel(const u16* __restrict__ qkv,
                                                      u16* __restrict__ att) {
    const int bid = blockIdx.x;
    const int h = bid & 15, b = (bid >> 4) & 7, e = bid >> 7;
    const int t = threadIdx.x;
    __shared__ u32 Ks[8192];   // 256 keys x 64 dims bf16
    __shared__ u32 Vs[8192];
    const size_t rowBase = ((size_t)e * MTOK + (size_t)b * NS) * 3072;
    const int kc = 1024 + h * 64, vc = 2048 + h * 64;
    #pragma unroll
    for (int i = 0; i < 32; i++) {
        int idx = t + 256 * i;
        int row = idx >> 5, c2 = (idx & 31) * 2;
        Ks[idx] = *(const u32*)(qkv + rowBase + (size_t)row * 3072 + kc + c2);
        Vs[idx] = *(const u32*)(qkv + rowBase + (size_t)row * 3072 + vc + c2);
    }
    float q[64];
    {
        const uint4* qp = (const uint4*)(qkv + rowBase + (size_t)t * 3072 + h * 64);
        #pragma unroll
        for (int i = 0; i < 8; i++) {
            uint4 u = qp[i];
            q[i*8+0] = bflo(u.x); q[i*8+1] = bfhi(u.x);
            q[i*8+2] = bflo(u.y); q[i*8+3] = bfhi(u.y);
            q[i*8+4] = bflo(u.z); q[i*8+5] = bfhi(u.z);
            q[i*8+6] = bflo(u.w); q[i*8+7] = bfhi(u.w);
        }
    }
    __syncthreads();
    float acc[64];
    #pragma unroll
    for (int d = 0; d < 64; d++) acc[d] = 0.f;
    float den = 0.f;
    for (int j = 0; j < 256; j++) {
        const uint4* kp = (const uint4*)&Ks[j * 32];
        float s = 0.f;
        #pragma unroll
        for (int i = 0; i < 8; i++) {
            uint4 u = kp[i];
            s += bflo(u.x)*q[i*8+0] + bfhi(u.x)*q[i*8+1]
               + bflo(u.y)*q[i*8+2] + bfhi(u.y)*q[i*8+3]
               + bflo(u.z)*q[i*8+4] + bfhi(u.z)*q[i*8+5]
               + bflo(u.w)*q[i*8+6] + bfhi(u.w)*q[i*8+7];
        }
        float p = __expf(s * 0.125f);   // scores small (~N(0,0.4)); no max-sub needed
        den += p;
        const uint4* vp = (const uint4*)&Vs[j * 32];
        #pragma unroll
        for (int i = 0; i < 8; i++) {
            uint4 u = vp[i];
            acc[i*8+0] += p * bflo(u.x); acc[i*8+1] += p * bfhi(u.x);
            acc[i*8+2] += p * bflo(u.y); acc[i*8+3] += p * bfhi(u.y);
            acc[i*8+4] += p * bflo(u.z); acc[i*8+5] += p * bfhi(u.z);
            acc[i*8+6] += p * bflo(u.w); acc[i*8+7] += p * bfhi(u.w);
        }
    }
    const float inv = 1.f / den;
    u16* op = att + ((size_t)e * MTOK + (size_t)b * NS + t) * NU + h * 64;
    #pragma unroll
    for (int i = 0; i < 32; i++)
        ((u32*)op)[i] = pack2(acc[2*i] * inv, acc[2*i+1] * inv);
}

// ---------------- persistent LSTM ----------------
// 256 WGs (grid==CU count => all co-resident). WG owns 16 hidden units of one expert.
// whh slice lives in registers as pre-formed MFMA B-fragments (wave g = gate g).
__global__ __launch_bounds__(256, 1) void lstm_kernel(
    const float* __restrict__ whh, const u16* __restrict__ xz,
    u32* __restrict__ hbuf,        // [2][E][B][512] u32 (bf16 unit-pairs)
    u16* __restrict__ mbuf,        // [E][MTOK][NU]
    u32* __restrict__ cnt)         // [E] cumulative barrier counters
{
    const int wg = blockIdx.x;
    const int e = wg >> 6;
    const int j0 = (wg & 63) * 16;
    const int t = threadIdx.x;
    const int g = t >> 6, lane = t & 63;
    const int quad = lane >> 4, l16 = lane & 15;

    __shared__ u16  hsh[16][1032];      // h staged bf16, rows 8..15 stay zero (MFMA pad)
    __shared__ float zbuf[4][16][8];    // [gate][unit][batch]
    __shared__ float cbuf[16][8];       // fp32 c state (persistent)

    for (int i = t; i < 16 * 1032; i += 256) (&hsh[0][0])[i] = 0;
    for (int i = t; i < 128; i += 256) (&cbuf[0][0])[i] = 0.f;

    // preload B-fragments: B[k][n] = whh[n][k]; lane n=l16, k=quad*8+j
    bfrag wf[32];
    const float* wrow = whh + ((size_t)e * 4096 + (size_t)g * 1024 + j0 + l16) * 1024 + quad * 8;
    #pragma unroll
    for (int kk = 0; kk < 32; kk++) {
        const float* p = wrow + kk * 32;
        float4 f0 = *(const float4*)p;
        float4 f1 = *(const float4*)(p + 4);
        union { u16 s[8]; bfrag v; } uu;
        uu.s[0]=f2bf(f0.x); uu.s[1]=f2bf(f0.y); uu.s[2]=f2bf(f0.z); uu.s[3]=f2bf(f0.w);
        uu.s[4]=f2bf(f1.x); uu.s[5]=f2bf(f1.y); uu.s[6]=f2bf(f1.z); uu.s[7]=f2bf(f1.w);
        wf[kk] = uu.v;
    }
    __syncthreads();

    u32* const myCnt = cnt + e;
    for (int st = 0; st < NS; st++) {
        // stage h(st) [8][1024] bf16 from coherent point
        const u32* hsrc = hbuf + ((size_t)(st & 1) * NE + e) * NB * 512;
        #pragma unroll
        for (int i = 0; i < 16; i++) {
            int idx = t + i * 256;
            u32 u = __hip_atomic_load(hsrc + idx, __ATOMIC_RELAXED, __HIP_MEMORY_SCOPE_AGENT);
            *(u32*)&hsh[idx >> 9][(idx & 511) * 2] = u;
        }
        __syncthreads();
        // zg partial = h @ whh_slice^T  (A = h[16 x 1024], one 16x16 n-tile per wave)
        f32x4 acc = {};
        #pragma unroll
        for (int kk = 0; kk < 32; kk++) {
            bfrag a = *(const bfrag*)&hsh[l16][kk * 32 + quad * 8];
            acc = __builtin_amdgcn_mfma_f32_16x16x32_bf16(a, wf[kk], acc, 0, 0, 0);
        }
        #pragma unroll
        for (int r = 0; r < 4; r++) {
            int bb = quad * 4 + r;
            if (bb < 8) zbuf[g][l16][bb] = acc[r];   // col=lane&15(unit), row=quad*4+r(batch)
        }
        __syncthreads();
        // gate math: 64 threads, each one (unit-pair, batch)
        if (t < 64) {
            const int jp = t >> 3, bb = t & 7;
            const int u0 = jp * 2;
            const u16* xp = xz + (((size_t)e * NS + st) * NB + bb) * 4096 + j0 + u0;
            u32 zi  = *(const u32*)(xp);
            u32 zf  = *(const u32*)(xp + 1024);
            u32 zgv = *(const u32*)(xp + 2048);
            u32 zo  = *(const u32*)(xp + 3072);
            float i0 = zbuf[0][u0][bb]   + bflo(zi);
            float i1 = zbuf[0][u0+1][bb] + bfhi(zi);
            float f0 = zbuf[1][u0][bb]   + bflo(zf);
            float f1 = zbuf[1][u0+1][bb] + bfhi(zf);
            float g0 = zbuf[2][u0][bb]   + bflo(zgv);
            float g1 = zbuf[2][u0+1][bb] + bfhi(zgv);
            float o0 = zbuf[3][u0][bb]   + bflo(zo);
            float o1 = zbuf[3][u0+1][bb] + bfhi(zo);
            float c0 = cbuf[u0][bb], c1 = cbuf[u0+1][bb];
            c0 = sigm(f0) * c0 + sigm(i0) * tanhf(g0);
            c1 = sigm(f1) * c1 + sigm(i1) * tanhf(g1);
            float h0 = sigm(o0) * tanhf(c0);
            float h1 = sigm(o1) * tanhf(c1);
            cbuf[u0][bb] = c0; cbuf[u0+1][bb] = c1;
            u32 hp = pack2(h0, h1);
            // hs output, token-major [e][b*256+st][u]
            *(u32*)(mbuf + (((size_t)e * NB + bb) * NS + st) * NU + j0 + u0) = hp;
            // h for next step -> coherent point (agent-scope atomic store)
            u32* hdst = hbuf + (((size_t)((st + 1) & 1) * NE + e) * NB + bb) * 512 + (j0 >> 1) + jp;
            __hip_atomic_store(hdst, hp, __ATOMIC_RELAXED, __HIP_MEMORY_SCOPE_AGENT);
        }
        __syncthreads();
        // per-expert barrier (cumulative count: 64 arrivals per step)
        if (t == 0) {
            __hip_atomic_fetch_add(myCnt, 1u, __ATOMIC_RELEASE, __HIP_MEMORY_SCOPE_AGENT);
            const u32 need = 64u * (u32)(st + 1);
            while (__hip_atomic_load(myCnt, __ATOMIC_ACQUIRE, __HIP_MEMORY_SCOPE_AGENT) < need) {
                __builtin_amdgcn_s_sleep(1);
            }
        }
        __syncthreads();
    }
}

// ---------------- final: per-expert LN + gate-weighted combine -> fp32 out ----------------
__global__ __launch_bounds__(256) void final_kernel(const u16* __restrict__ dec2,
                                                    const float* __restrict__ gam,
                                                    const float* __restrict__ bet,
                                                    const float* __restrict__ gates,
                                                    float* __restrict__ outp) {
    const int row = blockIdx.x;        // b*256+s
    const int b = row >> 8;
    const int t = threadIdx.x;
    const int wave = t >> 6, lane = t & 63;
    __shared__ float rb[4][2];
    float o0 = 0.f, o1 = 0.f, o2 = 0.f, o3 = 0.f;
    for (int e = 0; e < NE; e++) {
        uint2 u = *(const uint2*)(dec2 + ((size_t)e * MTOK + row) * ND + t * 4);
        float v0 = bflo(u.x), v1 = bfhi(u.x), v2 = bflo(u.y), v3 = bfhi(u.y);
        float s1 = v0 + v1 + v2 + v3;
        float s2 = v0*v0 + v1*v1 + v2*v2 + v3*v3;
        for (int o = 32; o; o >>= 1) { s1 += __shfl_down(s1, o); s2 += __shfl_down(s2, o); }
        __syncthreads();
        if (lane == 0) { rb[wave][0] = s1; rb[wave][1] = s2; }
        __syncthreads();
        s1 = rb[0][0] + rb[1][0] + rb[2][0] + rb[3][0];
        s2 = rb[0][1] + rb[1][1] + rb[2][1] + rb[3][1];
        const float mu = s1 * (1.f / ND);
        const float rstd = rsqrtf(s2 * (1.f / ND) - mu * mu + 1e-5f);
        const float ge = gates[b * NE + e];
        const float* gp = gam + e * ND + t * 4;
        const float* bp = bet + e * ND + t * 4;
        o0 += ge * ((v0 - mu) * rstd * gp[0] + bp[0]);
        o1 += ge * ((v1 - mu) * rstd * gp[1] + bp[1]);
        o2 += ge * ((v2 - mu) * rstd * gp[2] + bp[2]);
        o3 += ge * ((v3 - mu) * rstd * gp[3] + bp[3]);
    }
    float4 r; r.x = o0; r.y = o1; r.z = o2; r.w = o3;
    *(float4*)(outp + (size_t)row * ND + t * 4) = r;
}

// ---------------- workspace layout (bytes) ----------------
constexpr size_t OFF_WBUF  = 0;                       // 32MB: bf16 copy of current weight (max: wih)
constexpr size_t OFF_XBF   = 33554432;                // 4MB : x bf16
constexpr size_t OFF_A     = 37748736;                // 16MB: t1 / att / u1 / d1
constexpr size_t OFF_B     = 54525952;                // 16MB: t2 / att2 / o1
constexpr size_t OFF_HM    = 71303168;                // 16MB: h (enc LN out) then m (LSTM out)
constexpr size_t OFF_QX    = 88080384;                // 64MB: qkv then xz
constexpr size_t OFF_C     = 155189248;               // 16MB: u_ then dec2
constexpr size_t OFF_D     = 171966464;               // 16MB: gt
constexpr size_t OFF_XM    = 188743680;               // 32KB: pooled x
constexpr size_t OFF_GATES = 188776448;               // gates (pad 256)
constexpr size_t OFF_HBUF  = 188776704;               // 128KB: LSTM h ping-pong
constexpr size_t OFF_CNT   = 188907776;               // barrier counters

extern "C" void kernel_launch(void* const* d_in, const int* in_sizes, int n_in,
                              void* d_out, int out_size, void* d_ws, size_t ws_size,
                              hipStream_t stream) {
    const float* x        = (const float*)d_in[0];
    const float* router_w = (const float*)d_in[1];
    const float* router_b = (const float*)d_in[2];
    const float* enc_w1   = (const float*)d_in[3];
    const float* enc_b1   = (const float*)d_in[4];
    const float* enc_w2   = (const float*)d_in[5];
    const float* enc_b2   = (const float*)d_in[6];
    const float* enc_ln_g = (const float*)d_in[7];
    const float* enc_ln_b = (const float*)d_in[8];
    const float* wqkv     = (const float*)d_in[9];
    const float* bqkv     = (const float*)d_in[10];
    const float* wo       = (const float*)d_in[11];
    const float* bo       = (const float*)d_in[12];
    const float* wih      = (const float*)d_in[13];
    const float* whh      = (const float*)d_in[14];
    const float* bih      = (const float*)d_in[15];
    const float* bhh      = (const float*)d_in[16];
    const float* uw1      = (const float*)d_in[17];
    const float* ub1      = (const float*)d_in[18];
    const float* uw2      = (const float*)d_in[19];
    const float* ub2      = (const float*)d_in[20];
    const float* ow1      = (const float*)d_in[21];
    const float* ob1      = (const float*)d_in[22];
    const float* ow2      = (const float*)d_in[23];
    const float* ob2      = (const float*)d_in[24];
    const float* dw1      = (const float*)d_in[25];
    const float* db1      = (const float*)d_in[26];
    const float* dw2      = (const float*)d_in[27];
    const float* db2      = (const float*)d_in[28];
    const float* dec_ln_g = (const float*)d_in[29];
    const float* dec_ln_b = (const float*)d_in[30];

    char* W = (char*)d_ws;
    u16* wbuf   = (u16*)(W + OFF_WBUF);
    u16* x_bf   = (u16*)(W + OFF_XBF);
    u16* bufA   = (u16*)(W + OFF_A);
    u16* bufB   = (u16*)(W + OFF_B);
    u16* hm     = (u16*)(W + OFF_HM);
    u16* qx     = (u16*)(W + OFF_QX);
    u16* bufC   = (u16*)(W + OFF_C);
    u16* bufD   = (u16*)(W + OFF_D);
    float* xm   = (float*)(W + OFF_XM);
    float* gate = (float*)(W + OFF_GATES);
    u32* hbuf   = (u32*)(W + OFF_HBUF);
    u32* cnt    = (u32*)(W + OFF_CNT);

    // zero LSTM h ping-pong + barrier counters (ws is poisoned 0xAA each call)
    hipMemsetAsync(W + OFF_HBUF, 0, 131072 + 256, stream);

    const int nW1  = NE * NU * ND;      // 4M elems (1024x1024 weights)
    const int gW1  = nW1 / 2048;
    dim3 blk(256);

    // x -> bf16 ; router
    cvt_f32_bf16<<<MTOK * ND / 2048, blk, 0, stream>>>(x, x_bf, MTOK * ND);
    pool_kernel<<<32, blk, 0, stream>>>(x, xm);
    gates_kernel<<<NB, blk, 0, stream>>>(xm, router_w, router_b, gate);

    // encoder
    cvt_f32_bf16<<<gW1, blk, 0, stream>>>(enc_w1, wbuf, nW1);
    gemm_bt<1><<<dim3(16, 32, NE), blk, 0, stream>>>(x_bf, 0, wbuf, enc_b1, nullptr, nullptr, bufA, 1024, 1024);
    cvt_f32_bf16<<<gW1, blk, 0, stream>>>(enc_w2, wbuf, nW1);
    gemm_bt<0><<<dim3(16, 32, NE), blk, 0, stream>>>(bufA, 1, wbuf, enc_b2, nullptr, nullptr, bufB, 1024, 1024);
    ln_kernel<<<NE * MTOK, blk, 0, stream>>>(bufB, enc_ln_g, enc_ln_b, hm);

    // attention
    cvt_f32_bf16<<<3 * gW1, blk, 0, stream>>>(wqkv, wbuf, 3 * nW1);
    gemm_bt<0><<<dim3(48, 32, NE), blk, 0, stream>>>(hm, 1, wbuf, bqkv, nullptr, nullptr, qx, 3072, 1024);
    attn_kernel<<<NE * NB * 16, blk, 0, stream>>>(qx, bufA);
    cvt_f32_bf16<<<gW1, blk, 0, stream>>>(wo, wbuf, nW1);
    gemm_bt<0><<<dim3(16, 32, NE), blk, 0, stream>>>(bufA, 1, wbuf, bo, nullptr, nullptr, bufB, 1024, 1024);

    // LSTM input xz = att2 @ wih^T + bih + bhh, layout [e][s][b][4096]
    cvt_f32_bf16<<<4 * gW1, blk, 0, stream>>>(wih, wbuf, 4 * nW1);
    gemm_bt<4><<<dim3(64, 32, NE), blk, 0, stream>>>(bufB, 1, wbuf, bih, bhh, nullptr, qx, 4096, 1024);
    lstm_kernel<<<256, blk, 0, stream>>>(whh, qx, hbuf, hm, cnt);

    // understanding (sigmoid) & optimization (tanh) branches, gated product
    cvt_f32_bf16<<<gW1, blk, 0, stream>>>(uw1, wbuf, nW1);
    gemm_bt<1><<<dim3(16, 32, NE), blk, 0, stream>>>(hm, 1, wbuf, ub1, nullptr, nullptr, bufA, 1024, 1024);
    cvt_f32_bf16<<<gW1, blk, 0, stream>>>(uw2, wbuf, nW1);
    gemm_bt<2><<<dim3(16, 32, NE), blk, 0, stream>>>(bufA, 1, wbuf, ub2, nullptr, nullptr, bufC, 1024, 1024);
    cvt_f32_bf16<<<gW1, blk, 0, stream>>>(ow1, wbuf, nW1);
    gemm_bt<1><<<dim3(16, 32, NE), blk, 0, stream>>>(hm, 1, wbuf, ob1, nullptr, nullptr, bufB, 1024, 1024);
    cvt_f32_bf16<<<gW1, blk, 0, stream>>>(ow2, wbuf, nW1);
    gemm_bt<3><<<dim3(16, 32, NE), blk, 0, stream>>>(bufB, 1, wbuf, ob2, nullptr, bufC, bufD, 1024, 1024);

    // decoder
    cvt_f32_bf16<<<gW1, blk, 0, stream>>>(dw1, wbuf, nW1);
    gemm_bt<1><<<dim3(16, 32, NE), blk, 0, stream>>>(bufD, 1, wbuf, db1, nullptr, nullptr, bufA, 1024, 1024);
    cvt_f32_bf16<<<gW1, blk, 0, stream>>>(dw2, wbuf, nW1);
    gemm_bt<0><<<dim3(16, 32, NE), blk, 0, stream>>>(bufA, 1, wbuf, db2, nullptr, nullptr, bufC, 1024, 1024);

    // final LN + routed combine
    final_kernel<<<MTOK, blk, 0, stream>>>(bufC, dec_ln_g, dec_ln_b, gate, (float*)d_out);
}

// Round 2
// 4232.079 us; speedup vs baseline: 1.0581x; 1.0581x over previous
//
#include <hip/hip_runtime.h>
#include <stdint.h>

typedef unsigned short u16;
typedef unsigned int   u32;

// Problem constants
constexpr int NB   = 8;      // batch
constexpr int NS   = 256;    // seq
constexpr int ND   = 1024;   // input dim
constexpr int NU   = 1024;   // hidden dim
constexpr int NE   = 4;      // experts
constexpr int MTOK = NB * NS;  // 2048 token rows

typedef float f32x4 __attribute__((ext_vector_type(4)));
typedef short bfrag __attribute__((ext_vector_type(8)));   // 8 bf16 = 4 VGPRs

__device__ __forceinline__ u16 f2bf(float f) {
    u32 u = __builtin_bit_cast(u32, f);
    u32 r = (u + 0x7FFFu + ((u >> 16) & 1u)) >> 16;   // RNE
    return (u16)r;
}
__device__ __forceinline__ float bf2f(u16 h) { return __builtin_bit_cast(float, (u32)h << 16); }
__device__ __forceinline__ float bflo(u32 p) { return __builtin_bit_cast(float, p << 16); }
__device__ __forceinline__ float bfhi(u32 p) { return __builtin_bit_cast(float, p & 0xFFFF0000u); }
__device__ __forceinline__ u32 pack2(float a, float b) { return (u32)f2bf(a) | ((u32)f2bf(b) << 16); }
__device__ __forceinline__ float sigm(float x) { return 1.f / (1.f + __expf(-x)); }

// async global->LDS, 16B per lane. LDS dest must be wave-uniform (lane scatters +lane*16B).
__device__ __forceinline__ void g2l16(const u16* g, u16* l) {
    __builtin_amdgcn_global_load_lds((const __attribute__((address_space(1))) u32*)g,
                                     (__attribute__((address_space(3))) u32*)l, 16, 0, 0);
}

// ---------------- fp32 -> bf16 conversion (weights / x) ----------------
__global__ __launch_bounds__(256) void cvt_f32_bf16(const float* __restrict__ src,
                                                    u16* __restrict__ dst, int n) {
    int i = (blockIdx.x * 256 + threadIdx.x) * 8;
    if (i >= n) return;
    float4 a = *(const float4*)(src + i);
    float4 b = *(const float4*)(src + i + 4);
    uint4 o;
    o.x = pack2(a.x, a.y); o.y = pack2(a.z, a.w);
    o.z = pack2(b.x, b.y); o.w = pack2(b.z, b.w);
    *(uint4*)(dst + i) = o;
}

// ---------------- router: mean-pool + gates ----------------
__global__ __launch_bounds__(256) void pool_kernel(const float* __restrict__ x, float* __restrict__ xm) {
    int b = blockIdx.x >> 2;
    int d = (blockIdx.x & 3) * 256 + threadIdx.x;
    const float* xp = x + (size_t)b * NS * ND + d;
    float s = 0.f;
    for (int j = 0; j < NS; j++) s += xp[(size_t)j * ND];
    xm[b * ND + d] = s * (1.f / NS);
}

__global__ __launch_bounds__(256) void gates_kernel(const float* __restrict__ xm,
                                                    const float* __restrict__ rw,
                                                    const float* __restrict__ rb,
                                                    float* __restrict__ gates) {
    int b = blockIdx.x;
    int t = threadIdx.x;
    int e = t >> 6, lane = t & 63;
    float s = 0.f;
    for (int k = lane; k < ND; k += 64) s += xm[b * ND + k] * rw[e * ND + k];
    for (int o = 32; o; o >>= 1) s += __shfl_down(s, o);
    __shared__ float lg[NE];
    if (lane == 0) lg[e] = s + rb[e];
    __syncthreads();
    if (t == 0) {
        float m = fmaxf(fmaxf(lg[0], lg[1]), fmaxf(lg[2], lg[3]));
        float ex[NE]; float sum = 0.f;
        for (int i = 0; i < NE; i++) { ex[i] = __expf(lg[i] - m); sum += ex[i]; }
        for (int i = 0; i < NE; i++) gates[b * NE + i] = ex[i] / sum;
    }
}

// ---------------- GEMM (m97 structure): 128x128 tile, BK=32, global_load_lds w=16 ----------------
// out = act(A[M,K] @ W[N,K]^T + bias)
// MODE 0: none | 1: relu | 2: sigmoid | 3: tanh*mul | 4: xz layout, bias1+bias2
template<int MODE>
__global__ __launch_bounds__(256) void gemm_bt(
    const u16* __restrict__ A, int aPerExpert,
    const u16* __restrict__ Wt,
    const float* __restrict__ bias, const float* __restrict__ bias2,
    const u16* __restrict__ mul, u16* __restrict__ outp,
    int N, int K)
{
    const int e  = blockIdx.z;
    const int n0 = blockIdx.x * 128;
    const int m0 = blockIdx.y * 128;
    const int t  = threadIdx.x;
    const int wave = t >> 6, lane = t & 63;
    const int quad = lane >> 4, l16 = lane & 15;
    const int wm = (wave >> 1) * 64, wn = (wave & 1) * 64;

    __shared__ u16 As[128 * 32];   // contiguous (global_load_lds constraint: no padding)
    __shared__ u16 Bs[128 * 32];

    // staging map: wave stages rows [wave*32, wave*32+32) in two 16-row issues;
    // lane L -> row base+ (L>>2), col (L&3)*8  == lds base + L*16B
    const int sRow = wave * 32 + (lane >> 2);
    const int sCol = (lane & 3) * 8;
    const u16* aBase = A + (aPerExpert ? ((size_t)e * MTOK * K) : 0)
                         + (size_t)(m0 + sRow) * K + sCol;
    const u16* wBase = Wt + (size_t)e * N * K + (size_t)(n0 + sRow) * K + sCol;
    u16* const ldsA0 = &As[(wave * 32) * 32];
    u16* const ldsA1 = &As[(wave * 32 + 16) * 32];
    u16* const ldsB0 = &Bs[(wave * 32) * 32];
    u16* const ldsB1 = &Bs[(wave * 32 + 16) * 32];

    f32x4 acc[4][4] = {};

    for (int k0 = 0; k0 < K; k0 += 32) {
        if (k0) __syncthreads();                 // readers done with LDS
        g2l16(aBase + k0, ldsA0);
        g2l16(aBase + k0 + (size_t)16 * K, ldsA1);
        g2l16(wBase + k0, ldsB0);
        g2l16(wBase + k0 + (size_t)16 * K, ldsB1);
        __syncthreads();                         // vmcnt drain + barrier
        bfrag a[4], b[4];
        #pragma unroll
        for (int ti = 0; ti < 4; ti++)
            a[ti] = *(const bfrag*)&As[(wm + ti * 16 + l16) * 32 + quad * 8];
        #pragma unroll
        for (int tj = 0; tj < 4; tj++)
            b[tj] = *(const bfrag*)&Bs[(wn + tj * 16 + l16) * 32 + quad * 8];
        #pragma unroll
        for (int ti = 0; ti < 4; ti++)
            #pragma unroll
            for (int tj = 0; tj < 4; tj++)
                acc[ti][tj] = __builtin_amdgcn_mfma_f32_16x16x32_bf16(a[ti], b[tj], acc[ti][tj], 0, 0, 0);
    }

    #pragma unroll
    for (int ti = 0; ti < 4; ti++) {
        #pragma unroll
        for (int tj = 0; tj < 4; tj++) {
            const int gcol = n0 + wn + tj * 16 + l16;      // C/D col = lane&15
            float bv = bias ? bias[e * N + gcol] : 0.f;
            if (MODE == 4) bv += bias2[e * N + gcol];
            #pragma unroll
            for (int r = 0; r < 4; r++) {
                const int grow = m0 + wm + ti * 16 + quad * 4 + r;   // C/D row = quad*4+reg
                float v = acc[ti][tj][r] + bv;
                if (MODE == 1) v = fmaxf(v, 0.f);
                if (MODE == 2) v = 1.f / (1.f + __expf(-v));
                size_t idx;
                if (MODE == 4) {
                    // xz layout: [e][s][b][N]; token row grow = b*256+s
                    idx = ((((size_t)e * NS + (grow & 255)) * NB + (grow >> 8)) * (size_t)N) + gcol;
                } else {
                    idx = ((size_t)e * MTOK + grow) * (size_t)N + gcol;
                }
                if (MODE == 3) v = tanhf(v) * bf2f(mul[idx]);
                outp[idx] = f2bf(v);
            }
        }
    }
}

// ---------------- LayerNorm over last dim (1024), bf16 in/out ----------------
__global__ __launch_bounds__(256) void ln_kernel(const u16* __restrict__ xin,
                                                 const float* __restrict__ gam,
                                                 const float* __restrict__ bet,
                                                 u16* __restrict__ outp) {
    const int row = blockIdx.x;          // E*MTOK rows
    const int e = row >> 11;
    const int t = threadIdx.x;
    const int wave = t >> 6, lane = t & 63;
    uint2 u = *(const uint2*)(xin + (size_t)row * NU + t * 4);
    float v0 = bflo(u.x), v1 = bfhi(u.x), v2 = bflo(u.y), v3 = bfhi(u.y);
    float s1 = v0 + v1 + v2 + v3;
    float s2 = v0*v0 + v1*v1 + v2*v2 + v3*v3;
    for (int o = 32; o; o >>= 1) { s1 += __shfl_down(s1, o); s2 += __shfl_down(s2, o); }
    __shared__ float rb[4][2];
    if (lane == 0) { rb[wave][0] = s1; rb[wave][1] = s2; }
    __syncthreads();
    s1 = rb[0][0] + rb[1][0] + rb[2][0] + rb[3][0];
    s2 = rb[0][1] + rb[1][1] + rb[2][1] + rb[3][1];
    const float mu = s1 * (1.f / NU);
    const float rstd = rsqrtf(s2 * (1.f / NU) - mu * mu + 1e-5f);
    const float* gp = gam + e * NU + t * 4;
    const float* bp = bet + e * NU + t * 4;
    uint2 o;
    o.x = pack2((v0 - mu) * rstd * gp[0] + bp[0], (v1 - mu) * rstd * gp[1] + bp[1]);
    o.y = pack2((v2 - mu) * rstd * gp[2] + bp[2], (v3 - mu) * rstd * gp[3] + bp[3]);
    *(uint2*)(outp + (size_t)row * NU + t * 4) = o;
}

// ---------------- attention: one WG per (e,b,h); thread = query row ----------------
__global__ __launch_bounds__(256, 2) void attn_kernel(const u16* __restrict__ qkv,
                                                      u16* __restrict__ att) {
    const int bid = blockIdx.x;
    const int h = bid & 15, b = (bid >> 4) & 7, e = bid >> 7;
    const int t = threadIdx.x;
    __shared__ u32 Ks[8192];   // 256 keys x 64 dims bf16
    __shared__ u32 Vs[8192];
    const size_t rowBase = ((size_t)e * MTOK + (size_t)b * NS) * 3072;
    const int kc = 1024 + h * 64, vc = 2048 + h * 64;
    #pragma unroll
    for (int i = 0; i < 32; i++) {
        int idx = t + 256 * i;
        int row = idx >> 5, c2 = (idx & 31) * 2;
        Ks[idx] = *(const u32*)(qkv + rowBase + (size_t)row * 3072 + kc + c2);
        Vs[idx] = *(const u32*)(qkv + rowBase + (size_t)row * 3072 + vc + c2);
    }
    float q[64];
    {
        const uint4* qp = (const uint4*)(qkv + rowBase + (size_t)t * 3072 + h * 64);
        #pragma unroll
        for (int i = 0; i < 8; i++) {
            uint4 u = qp[i];
            q[i*8+0] = bflo(u.x); q[i*8+1] = bfhi(u.x);
            q[i*8+2] = bflo(u.y); q[i*8+3] = bfhi(u.y);
            q[i*8+4] = bflo(u.z); q[i*8+5] = bfhi(u.z);
            q[i*8+6] = bflo(u.w); q[i*8+7] = bfhi(u.w);
        }
    }
    __syncthreads();
    float acc[64];
    #pragma unroll
    for (int d = 0; d < 64; d++) acc[d] = 0.f;
    float den = 0.f;
    for (int j = 0; j < 256; j++) {
        const uint4* kp = (const uint4*)&Ks[j * 32];
        float s = 0.f;
        #pragma unroll
        for (int i = 0; i < 8; i++) {
            uint4 u = kp[i];
            s += bflo(u.x)*q[i*8+0] + bfhi(u.x)*q[i*8+1]
               + bflo(u.y)*q[i*8+2] + bfhi(u.y)*q[i*8+3]
               + bflo(u.z)*q[i*8+4] + bfhi(u.z)*q[i*8+5]
               + bflo(u.w)*q[i*8+6] + bfhi(u.w)*q[i*8+7];
        }
        float p = __expf(s * 0.125f);
        den += p;
        const uint4* vp = (const uint4*)&Vs[j * 32];
        #pragma unroll
        for (int i = 0; i < 8; i++) {
            uint4 u = vp[i];
            acc[i*8+0] += p * bflo(u.x); acc[i*8+1] += p * bfhi(u.x);
            acc[i*8+2] += p * bflo(u.y); acc[i*8+3] += p * bfhi(u.y);
            acc[i*8+4] += p * bflo(u.z); acc[i*8+5] += p * bfhi(u.z);
            acc[i*8+6] += p * bflo(u.w); acc[i*8+7] += p * bfhi(u.w);
        }
    }
    const float inv = 1.f / den;
    u16* op = att + ((size_t)e * MTOK + (size_t)b * NS + t) * NU + h * 64;
    #pragma unroll
    for (int i = 0; i < 32; i++)
        ((u32*)op)[i] = pack2(acc[2*i] * inv, acc[2*i+1] * inv);
}

// ---------------- persistent LSTM ----------------
// 256 WGs co-resident. WG owns 16 hidden units of one expert; whh slice in registers.
// Flag-vector barrier: 64 independent release-stores + 64-lane acquire poll (no RMW chain).
__global__ __launch_bounds__(256, 1) void lstm_kernel(
    const float* __restrict__ whh, const u16* __restrict__ xz,
    u32* __restrict__ hbuf,        // [2][E][64 wg][64] u32 (bf16 unit-pairs, contiguous per WG)
    u16* __restrict__ mbuf,        // [E][MTOK][NU]
    u32* __restrict__ flags)       // [E][64] per-WG step flags
{
    const int wg = blockIdx.x;
    const int e = wg >> 6;
    const int w63 = wg & 63;
    const int j0 = w63 * 16;
    const int t = threadIdx.x;
    const int g = t >> 6, lane = t & 63;
    const int quad = lane >> 4, l16 = lane & 15;

    __shared__ u16  hsh[16][1032];      // h staged bf16, rows 8..15 stay zero (MFMA pad)
    __shared__ float zbuf[4][16][8];    // [gate][unit][batch]
    __shared__ float cbuf[16][8];       // fp32 c state (persistent)

    for (int i = t; i < 16 * 1032; i += 256) (&hsh[0][0])[i] = 0;
    for (int i = t; i < 128; i += 256) (&cbuf[0][0])[i] = 0.f;

    // preload B-fragments: B[k][n] = whh[n][k]; lane n=l16, k=quad*8+j
    bfrag wf[32];
    const float* wrow = whh + ((size_t)e * 4096 + (size_t)g * 1024 + j0 + l16) * 1024 + quad * 8;
    #pragma unroll
    for (int kk = 0; kk < 32; kk++) {
        const float* p = wrow + kk * 32;
        float4 f0 = *(const float4*)p;
        float4 f1 = *(const float4*)(p + 4);
        union { u16 s[8]; bfrag v; } uu;
        uu.s[0]=f2bf(f0.x); uu.s[1]=f2bf(f0.y); uu.s[2]=f2bf(f0.z); uu.s[3]=f2bf(f0.w);
        uu.s[4]=f2bf(f1.x); uu.s[5]=f2bf(f1.y); uu.s[6]=f2bf(f1.z); uu.s[7]=f2bf(f1.w);
        wf[kk] = uu.v;
    }
    __syncthreads();

    for (int st = 0; st < NS; st++) {
        // xz loads for this step issued FIRST (independent of h exchange)
        u32 zi, zf, zgv, zo;
        const int jp = t >> 3, bb = t & 7, u0 = (t >> 3) * 2;
        if (t < 64) {
            const u16* xp = xz + (((size_t)e * NS + st) * NB + bb) * 4096 + j0 + u0;
            zi  = *(const u32*)(xp);
            zf  = *(const u32*)(xp + 1024);
            zgv = *(const u32*)(xp + 2048);
            zo  = *(const u32*)(xp + 3072);
        }
        // stage h(st): hbuf block layout [w:6][jp:3][bb:3]; hsh[row=batch][col=unit]
        const u32* hsrc = hbuf + ((size_t)(st & 1) * NE + e) * 4096;
        #pragma unroll
        for (int i = 0; i < 16; i++) {
            int idx = t + i * 256;
            u32 u = __hip_atomic_load(hsrc + idx, __ATOMIC_RELAXED, __HIP_MEMORY_SCOPE_AGENT);
            int sw = idx >> 6, sjp = (idx >> 3) & 7, sbb = idx & 7;
            *(u32*)&hsh[sbb][(sw * 8 + sjp) * 2] = u;
        }
        __syncthreads();
        // zg partial = h @ whh_slice^T  (A = h[16 x 1024], one 16x16 n-tile per wave)
        f32x4 acc = {};
        #pragma unroll
        for (int kk = 0; kk < 32; kk++) {
            bfrag a = *(const bfrag*)&hsh[l16][kk * 32 + quad * 8];
            acc = __builtin_amdgcn_mfma_f32_16x16x32_bf16(a, wf[kk], acc, 0, 0, 0);
        }
        #pragma unroll
        for (int r = 0; r < 4; r++) {
            int rb = quad * 4 + r;
            if (rb < 8) zbuf[g][l16][rb] = acc[r];   // col=lane&15(unit), row=quad*4+r(batch)
        }
        __syncthreads();
        // gate math: 64 threads (wave 0), each one (unit-pair, batch)
        if (t < 64) {
            float i0 = zbuf[0][u0][bb]   + bflo(zi);
            float i1 = zbuf[0][u0+1][bb] + bfhi(zi);
            float f0 = zbuf[1][u0][bb]   + bflo(zf);
            float f1 = zbuf[1][u0+1][bb] + bfhi(zf);
            float g0 = zbuf[2][u0][bb]   + bflo(zgv);
            float g1 = zbuf[2][u0+1][bb] + bfhi(zgv);
            float o0 = zbuf[3][u0][bb]   + bflo(zo);
            float o1 = zbuf[3][u0+1][bb] + bfhi(zo);
            float c0 = cbuf[u0][bb], c1 = cbuf[u0+1][bb];
            c0 = sigm(f0) * c0 + sigm(i0) * tanhf(g0);
            c1 = sigm(f1) * c1 + sigm(i1) * tanhf(g1);
            float h0 = sigm(o0) * tanhf(c0);
            float h1 = sigm(o1) * tanhf(c1);
            cbuf[u0][bb] = c0; cbuf[u0+1][bb] = c1;
            u32 hp = pack2(h0, h1);
            // hs output, token-major [e][b*256+st][u]
            *(u32*)(mbuf + (((size_t)e * NB + bb) * NS + st) * NU + j0 + u0) = hp;
            if (st < NS - 1) {
                // h for next step: contiguous 256B block per WG
                u32* hdst = hbuf + ((size_t)((st + 1) & 1) * NE + e) * 4096 + w63 * 64 + t;
                __hip_atomic_store(hdst, hp, __ATOMIC_RELAXED, __HIP_MEMORY_SCOPE_AGENT);
                // release AFTER wave's h stores drain (vmcnt is wave-wide)
                if (t == 0)
                    __hip_atomic_store(flags + e * 64 + w63, (u32)(st + 1),
                                       __ATOMIC_RELEASE, __HIP_MEMORY_SCOPE_AGENT);
                // poll: lane t watches WG t of this expert
                const u32 tgt = (u32)(st + 1);
                while (true) {
                    u32 f = __hip_atomic_load(flags + e * 64 + t,
                                              __ATOMIC_ACQUIRE, __HIP_MEMORY_SCOPE_AGENT);
                    if (__all((int)(f >= tgt))) break;
                    __builtin_amdgcn_s_sleep(1);
                }
            }
        }
        __syncthreads();
    }
}

// ---------------- final: per-expert LN + gate-weighted combine -> fp32 out ----------------
__global__ __launch_bounds__(256) void final_kernel(const u16* __restrict__ dec2,
                                                    const float* __restrict__ gam,
                                                    const float* __restrict__ bet,
                                                    const float* __restrict__ gates,
                                                    float* __restrict__ outp) {
    const int row = blockIdx.x;        // b*256+s
    const int b = row >> 8;
    const int t = threadIdx.x;
    const int wave = t >> 6, lane = t & 63;
    __shared__ float rb[4][2];
    float o0 = 0.f, o1 = 0.f, o2 = 0.f, o3 = 0.f;
    for (int e = 0; e < NE; e++) {
        uint2 u = *(const uint2*)(dec2 + ((size_t)e * MTOK + row) * ND + t * 4);
        float v0 = bflo(u.x), v1 = bfhi(u.x), v2 = bflo(u.y), v3 = bfhi(u.y);
        float s1 = v0 + v1 + v2 + v3;
        float s2 = v0*v0 + v1*v1 + v2*v2 + v3*v3;
        for (int o = 32; o; o >>= 1) { s1 += __shfl_down(s1, o); s2 += __shfl_down(s2, o); }
        __syncthreads();
        if (lane == 0) { rb[wave][0] = s1; rb[wave][1] = s2; }
        __syncthreads();
        s1 = rb[0][0] + rb[1][0] + rb[2][0] + rb[3][0];
        s2 = rb[0][1] + rb[1][1] + rb[2][1] + rb[3][1];
        const float mu = s1 * (1.f / ND);
        const float rstd = rsqrtf(s2 * (1.f / ND) - mu * mu + 1e-5f);
        const float ge = gates[b * NE + e];
        const float* gp = gam + e * ND + t * 4;
        const float* bp = bet + e * ND + t * 4;
        o0 += ge * ((v0 - mu) * rstd * gp[0] + bp[0]);
        o1 += ge * ((v1 - mu) * rstd * gp[1] + bp[1]);
        o2 += ge * ((v2 - mu) * rstd * gp[2] + bp[2]);
        o3 += ge * ((v3 - mu) * rstd * gp[3] + bp[3]);
    }
    float4 r; r.x = o0; r.y = o1; r.z = o2; r.w = o3;
    *(float4*)(outp + (size_t)row * ND + t * 4) = r;
}

// ---------------- workspace layout (bytes) ----------------
constexpr size_t OFF_WBUF  = 0;                       // 32MB: bf16 copy of current weight (max: wih)
constexpr size_t OFF_XBF   = 33554432;                // 4MB : x bf16
constexpr size_t OFF_A     = 37748736;                // 16MB: t1 / att / u1 / d1
constexpr size_t OFF_B     = 54525952;                // 16MB: t2 / att2 / o1
constexpr size_t OFF_HM    = 71303168;                // 16MB: h (enc LN out) then m (LSTM out)
constexpr size_t OFF_QX    = 88080384;                // 64MB: qkv then xz
constexpr size_t OFF_C     = 155189248;               // 16MB: u_ then dec2
constexpr size_t OFF_D     = 171966464;               // 16MB: gt
constexpr size_t OFF_XM    = 188743680;               // 32KB: pooled x
constexpr size_t OFF_GATES = 188776448;               // gates (pad 256)
constexpr size_t OFF_HBUF  = 188776704;               // 128KB: LSTM h ping-pong
constexpr size_t OFF_FLAGS = 188907776;               // 1KB: per-WG step flags

extern "C" void kernel_launch(void* const* d_in, const int* in_sizes, int n_in,
                              void* d_out, int out_size, void* d_ws, size_t ws_size,
                              hipStream_t stream) {
    const float* x        = (const float*)d_in[0];
    const float* router_w = (const float*)d_in[1];
    const float* router_b = (const float*)d_in[2];
    const float* enc_w1   = (const float*)d_in[3];
    const float* enc_b1   = (const float*)d_in[4];
    const float* enc_w2   = (const float*)d_in[5];
    const float* enc_b2   = (const float*)d_in[6];
    const float* enc_ln_g = (const float*)d_in[7];
    const float* enc_ln_b = (const float*)d_in[8];
    const float* wqkv     = (const float*)d_in[9];
    const float* bqkv     = (const float*)d_in[10];
    const float* wo       = (const float*)d_in[11];
    const float* bo       = (const float*)d_in[12];
    const float* wih      = (const float*)d_in[13];
    const float* whh      = (const float*)d_in[14];
    const float* bih      = (const float*)d_in[15];
    const float* bhh      = (const float*)d_in[16];
    const float* uw1      = (const float*)d_in[17];
    const float* ub1      = (const float*)d_in[18];
    const float* uw2      = (const float*)d_in[19];
    const float* ub2      = (const float*)d_in[20];
    const float* ow1      = (const float*)d_in[21];
    const float* ob1      = (const float*)d_in[22];
    const float* ow2      = (const float*)d_in[23];
    const float* ob2      = (const float*)d_in[24];
    const float* dw1      = (const float*)d_in[25];
    const float* db1      = (const float*)d_in[26];
    const float* dw2      = (const float*)d_in[27];
    const float* db2      = (const float*)d_in[28];
    const float* dec_ln_g = (const float*)d_in[29];
    const float* dec_ln_b = (const float*)d_in[30];

    char* W = (char*)d_ws;
    u16* wbuf   = (u16*)(W + OFF_WBUF);
    u16* x_bf   = (u16*)(W + OFF_XBF);
    u16* bufA   = (u16*)(W + OFF_A);
    u16* bufB   = (u16*)(W + OFF_B);
    u16* hm     = (u16*)(W + OFF_HM);
    u16* qx     = (u16*)(W + OFF_QX);
    u16* bufC   = (u16*)(W + OFF_C);
    u16* bufD   = (u16*)(W + OFF_D);
    float* xm   = (float*)(W + OFF_XM);
    float* gate = (float*)(W + OFF_GATES);
    u32* hbuf   = (u32*)(W + OFF_HBUF);
    u32* flags  = (u32*)(W + OFF_FLAGS);

    // zero LSTM h ping-pong + flags (ws is poisoned 0xAA each call)
    hipMemsetAsync(W + OFF_HBUF, 0, 131072 + 4096, stream);

    const int nW1  = NE * NU * ND;      // 4M elems (1024x1024 weights)
    const int gW1  = nW1 / 2048;
    dim3 blk(256);

    // x -> bf16 ; router
    cvt_f32_bf16<<<MTOK * ND / 2048, blk, 0, stream>>>(x, x_bf, MTOK * ND);
    pool_kernel<<<32, blk, 0, stream>>>(x, xm);
    gates_kernel<<<NB, blk, 0, stream>>>(xm, router_w, router_b, gate);

    // encoder
    cvt_f32_bf16<<<gW1, blk, 0, stream>>>(enc_w1, wbuf, nW1);
    gemm_bt<1><<<dim3(8, 16, NE), blk, 0, stream>>>(x_bf, 0, wbuf, enc_b1, nullptr, nullptr, bufA, 1024, 1024);
    cvt_f32_bf16<<<gW1, blk, 0, stream>>>(enc_w2, wbuf, nW1);
    gemm_bt<0><<<dim3(8, 16, NE), blk, 0, stream>>>(bufA, 1, wbuf, enc_b2, nullptr, nullptr, bufB, 1024, 1024);
    ln_kernel<<<NE * MTOK, blk, 0, stream>>>(bufB, enc_ln_g, enc_ln_b, hm);

    // attention
    cvt_f32_bf16<<<3 * gW1, blk, 0, stream>>>(wqkv, wbuf, 3 * nW1);
    gemm_bt<0><<<dim3(24, 16, NE), blk, 0, stream>>>(hm, 1, wbuf, bqkv, nullptr, nullptr, qx, 3072, 1024);
    attn_kernel<<<NE * NB * 16, blk, 0, stream>>>(qx, bufA);
    cvt_f32_bf16<<<gW1, blk, 0, stream>>>(wo, wbuf, nW1);
    gemm_bt<0><<<dim3(8, 16, NE), blk, 0, stream>>>(bufA, 1, wbuf, bo, nullptr, nullptr, bufB, 1024, 1024);

    // LSTM input xz = att2 @ wih^T + bih + bhh, layout [e][s][b][4096]
    cvt_f32_bf16<<<4 * gW1, blk, 0, stream>>>(wih, wbuf, 4 * nW1);
    gemm_bt<4><<<dim3(32, 16, NE), blk, 0, stream>>>(bufB, 1, wbuf, bih, bhh, nullptr, qx, 4096, 1024);
    lstm_kernel<<<256, blk, 0, stream>>>(whh, qx, hbuf, hm, flags);

    // understanding (sigmoid) & optimization (tanh) branches, gated product
    cvt_f32_bf16<<<gW1, blk, 0, stream>>>(uw1, wbuf, nW1);
    gemm_bt<1><<<dim3(8, 16, NE), blk, 0, stream>>>(hm, 1, wbuf, ub1, nullptr, nullptr, bufA, 1024, 1024);
    cvt_f32_bf16<<<gW1, blk, 0, stream>>>(uw2, wbuf, nW1);
    gemm_bt<2><<<dim3(8, 16, NE), blk, 0, stream>>>(bufA, 1, wbuf, ub2, nullptr, nullptr, bufC, 1024, 1024);
    cvt_f32_bf16<<<gW1, blk, 0, stream>>>(ow1, wbuf, nW1);
    gemm_bt<1><<<dim3(8, 16, NE), blk, 0, stream>>>(hm, 1, wbuf, ob1, nullptr, nullptr, bufB, 1024, 1024);
    cvt_f32_bf16<<<gW1, blk, 0, stream>>>(ow2, wbuf, nW1);
    gemm_bt<3><<<dim3(8, 16, NE), blk, 0, stream>>>(bufB, 1, wbuf, ob2, nullptr, bufC, bufD, 1024, 1024);

    // decoder
    cvt_f32_bf16<<<gW1, blk, 0, stream>>>(dw1, wbuf, nW1);
    gemm_bt<1><<<dim3(8, 16, NE), blk, 0, stream>>>(bufD, 1, wbuf, db1, nullptr, nullptr, bufA, 1024, 1024);
    cvt_f32_bf16<<<gW1, blk, 0, stream>>>(dw2, wbuf, nW1);
    gemm_bt<0><<<dim3(8, 16, NE), blk, 0, stream>>>(bufA, 1, wbuf, db2, nullptr, nullptr, bufC, 1024, 1024);

    // final LN + routed combine
    final_kernel<<<MTOK, blk, 0, stream>>>(bufC, dec_ln_g, dec_ln_b, gate, (float*)d_out);
}

// Round 3
// 2722.481 us; speedup vs baseline: 1.6448x; 1.5545x over previous
//
#include <hip/hip_runtime.h>
#include <stdint.h>

typedef unsigned short u16;
typedef unsigned int   u32;
typedef unsigned long long u64;

// Problem constants
constexpr int NB   = 8;      // batch
constexpr int NS   = 256;    // seq
constexpr int ND   = 1024;   // input dim
constexpr int NU   = 1024;   // hidden dim
constexpr int NE   = 4;      // experts
constexpr int MTOK = NB * NS;  // 2048 token rows

typedef float f32x4 __attribute__((ext_vector_type(4)));
typedef short bfrag __attribute__((ext_vector_type(8)));   // 8 bf16 = 4 VGPRs

__device__ __forceinline__ u16 f2bf(float f) {
    u32 u = __builtin_bit_cast(u32, f);
    u32 r = (u + 0x7FFFu + ((u >> 16) & 1u)) >> 16;   // RNE
    return (u16)r;
}
__device__ __forceinline__ float bf2f(u16 h) { return __builtin_bit_cast(float, (u32)h << 16); }
__device__ __forceinline__ float bflo(u32 p) { return __builtin_bit_cast(float, p << 16); }
__device__ __forceinline__ float bfhi(u32 p) { return __builtin_bit_cast(float, p & 0xFFFF0000u); }
__device__ __forceinline__ u32 pack2(float a, float b) { return (u32)f2bf(a) | ((u32)f2bf(b) << 16); }
__device__ __forceinline__ float sigm(float x) { return 1.f / (1.f + __expf(-x)); }

// async global->LDS, 16B per lane. LDS dest must be wave-uniform (lane scatters +lane*16B).
__device__ __forceinline__ void g2l16(const u16* g, u16* l) {
    __builtin_amdgcn_global_load_lds((const __attribute__((address_space(1))) u32*)g,
                                     (__attribute__((address_space(3))) u32*)l, 16, 0, 0);
}

// ---------------- fp32 -> bf16 conversion (weights / x) ----------------
__global__ __launch_bounds__(256) void cvt_f32_bf16(const float* __restrict__ src,
                                                    u16* __restrict__ dst, int n) {
    int i = (blockIdx.x * 256 + threadIdx.x) * 8;
    if (i >= n) return;
    float4 a = *(const float4*)(src + i);
    float4 b = *(const float4*)(src + i + 4);
    uint4 o;
    o.x = pack2(a.x, a.y); o.y = pack2(a.z, a.w);
    o.z = pack2(b.x, b.y); o.w = pack2(b.z, b.w);
    *(uint4*)(dst + i) = o;
}

// ---------------- router: mean-pool + gates ----------------
__global__ __launch_bounds__(256) void pool_kernel(const float* __restrict__ x, float* __restrict__ xm) {
    int b = blockIdx.x >> 2;
    int d = (blockIdx.x & 3) * 256 + threadIdx.x;
    const float* xp = x + (size_t)b * NS * ND + d;
    float s = 0.f;
    for (int j = 0; j < NS; j++) s += xp[(size_t)j * ND];
    xm[b * ND + d] = s * (1.f / NS);
}

__global__ __launch_bounds__(256) void gates_kernel(const float* __restrict__ xm,
                                                    const float* __restrict__ rw,
                                                    const float* __restrict__ rb,
                                                    float* __restrict__ gates) {
    int b = blockIdx.x;
    int t = threadIdx.x;
    int e = t >> 6, lane = t & 63;
    float s = 0.f;
    for (int k = lane; k < ND; k += 64) s += xm[b * ND + k] * rw[e * ND + k];
    for (int o = 32; o; o >>= 1) s += __shfl_down(s, o);
    __shared__ float lg[NE];
    if (lane == 0) lg[e] = s + rb[e];
    __syncthreads();
    if (t == 0) {
        float m = fmaxf(fmaxf(lg[0], lg[1]), fmaxf(lg[2], lg[3]));
        float ex[NE]; float sum = 0.f;
        for (int i = 0; i < NE; i++) { ex[i] = __expf(lg[i] - m); sum += ex[i]; }
        for (int i = 0; i < NE; i++) gates[b * NE + i] = ex[i] / sum;
    }
}

// ---------------- GEMM (m97 structure): 128x128 tile, BK=32, global_load_lds w=16 ----------------
// out = act(A[M,K] @ W[N,K]^T + bias)
// MODE 0: none | 1: relu | 2: sigmoid | 3: tanh*mul | 4: xz layout, bias1+bias2
template<int MODE>
__global__ __launch_bounds__(256) void gemm_bt(
    const u16* __restrict__ A, int aPerExpert,
    const u16* __restrict__ Wt,
    const float* __restrict__ bias, const float* __restrict__ bias2,
    const u16* __restrict__ mul, u16* __restrict__ outp,
    int N, int K)
{
    const int e  = blockIdx.z;
    const int n0 = blockIdx.x * 128;
    const int m0 = blockIdx.y * 128;
    const int t  = threadIdx.x;
    const int wave = t >> 6, lane = t & 63;
    const int quad = lane >> 4, l16 = lane & 15;
    const int wm = (wave >> 1) * 64, wn = (wave & 1) * 64;

    __shared__ u16 As[128 * 32];   // contiguous (global_load_lds constraint: no padding)
    __shared__ u16 Bs[128 * 32];

    const int sRow = wave * 32 + (lane >> 2);
    const int sCol = (lane & 3) * 8;
    const u16* aBase = A + (aPerExpert ? ((size_t)e * MTOK * K) : 0)
                         + (size_t)(m0 + sRow) * K + sCol;
    const u16* wBase = Wt + (size_t)e * N * K + (size_t)(n0 + sRow) * K + sCol;
    u16* const ldsA0 = &As[(wave * 32) * 32];
    u16* const ldsA1 = &As[(wave * 32 + 16) * 32];
    u16* const ldsB0 = &Bs[(wave * 32) * 32];
    u16* const ldsB1 = &Bs[(wave * 32 + 16) * 32];

    f32x4 acc[4][4] = {};

    for (int k0 = 0; k0 < K; k0 += 32) {
        if (k0) __syncthreads();                 // readers done with LDS
        g2l16(aBase + k0, ldsA0);
        g2l16(aBase + k0 + (size_t)16 * K, ldsA1);
        g2l16(wBase + k0, ldsB0);
        g2l16(wBase + k0 + (size_t)16 * K, ldsB1);
        __syncthreads();                         // vmcnt drain + barrier
        bfrag a[4], b[4];
        #pragma unroll
        for (int ti = 0; ti < 4; ti++)
            a[ti] = *(const bfrag*)&As[(wm + ti * 16 + l16) * 32 + quad * 8];
        #pragma unroll
        for (int tj = 0; tj < 4; tj++)
            b[tj] = *(const bfrag*)&Bs[(wn + tj * 16 + l16) * 32 + quad * 8];
        #pragma unroll
        for (int ti = 0; ti < 4; ti++)
            #pragma unroll
            for (int tj = 0; tj < 4; tj++)
                acc[ti][tj] = __builtin_amdgcn_mfma_f32_16x16x32_bf16(a[ti], b[tj], acc[ti][tj], 0, 0, 0);
    }

    #pragma unroll
    for (int ti = 0; ti < 4; ti++) {
        #pragma unroll
        for (int tj = 0; tj < 4; tj++) {
            const int gcol = n0 + wn + tj * 16 + l16;      // C/D col = lane&15
            float bv = bias ? bias[e * N + gcol] : 0.f;
            if (MODE == 4) bv += bias2[e * N + gcol];
            #pragma unroll
            for (int r = 0; r < 4; r++) {
                const int grow = m0 + wm + ti * 16 + quad * 4 + r;   // C/D row = quad*4+reg
                float v = acc[ti][tj][r] + bv;
                if (MODE == 1) v = fmaxf(v, 0.f);
                if (MODE == 2) v = 1.f / (1.f + __expf(-v));
                size_t idx;
                if (MODE == 4) {
                    // xz layout: [e][s][b][N]; token row grow = b*256+s
                    idx = ((((size_t)e * NS + (grow & 255)) * NB + (grow >> 8)) * (size_t)N) + gcol;
                } else {
                    idx = ((size_t)e * MTOK + grow) * (size_t)N + gcol;
                }
                if (MODE == 3) v = tanhf(v) * bf2f(mul[idx]);
                outp[idx] = f2bf(v);
            }
        }
    }
}

// ---------------- LayerNorm over last dim (1024), bf16 in/out ----------------
__global__ __launch_bounds__(256) void ln_kernel(const u16* __restrict__ xin,
                                                 const float* __restrict__ gam,
                                                 const float* __restrict__ bet,
                                                 u16* __restrict__ outp) {
    const int row = blockIdx.x;          // E*MTOK rows
    const int e = row >> 11;
    const int t = threadIdx.x;
    const int wave = t >> 6, lane = t & 63;
    uint2 u = *(const uint2*)(xin + (size_t)row * NU + t * 4);
    float v0 = bflo(u.x), v1 = bfhi(u.x), v2 = bflo(u.y), v3 = bfhi(u.y);
    float s1 = v0 + v1 + v2 + v3;
    float s2 = v0*v0 + v1*v1 + v2*v2 + v3*v3;
    for (int o = 32; o; o >>= 1) { s1 += __shfl_down(s1, o); s2 += __shfl_down(s2, o); }
    __shared__ float rb[4][2];
    if (lane == 0) { rb[wave][0] = s1; rb[wave][1] = s2; }
    __syncthreads();
    s1 = rb[0][0] + rb[1][0] + rb[2][0] + rb[3][0];
    s2 = rb[0][1] + rb[1][1] + rb[2][1] + rb[3][1];
    const float mu = s1 * (1.f / NU);
    const float rstd = rsqrtf(s2 * (1.f / NU) - mu * mu + 1e-5f);
    const float* gp = gam + e * NU + t * 4;
    const float* bp = bet + e * NU + t * 4;
    uint2 o;
    o.x = pack2((v0 - mu) * rstd * gp[0] + bp[0], (v1 - mu) * rstd * gp[1] + bp[1]);
    o.y = pack2((v2 - mu) * rstd * gp[2] + bp[2], (v3 - mu) * rstd * gp[3] + bp[3]);
    *(uint2*)(outp + (size_t)row * NU + t * 4) = o;
}

// ---------------- attention: one WG per (e,b,h); thread = query row ----------------
__global__ __launch_bounds__(256, 2) void attn_kernel(const u16* __restrict__ qkv,
                                                      u16* __restrict__ att) {
    const int bid = blockIdx.x;
    const int h = bid & 15, b = (bid >> 4) & 7, e = bid >> 7;
    const int t = threadIdx.x;
    __shared__ u32 Ks[8192];   // 256 keys x 64 dims bf16
    __shared__ u32 Vs[8192];
    const size_t rowBase = ((size_t)e * MTOK + (size_t)b * NS) * 3072;
    const int kc = 1024 + h * 64, vc = 2048 + h * 64;
    #pragma unroll
    for (int i = 0; i < 32; i++) {
        int idx = t + 256 * i;
        int row = idx >> 5, c2 = (idx & 31) * 2;
        Ks[idx] = *(const u32*)(qkv + rowBase + (size_t)row * 3072 + kc + c2);
        Vs[idx] = *(const u32*)(qkv + rowBase + (size_t)row * 3072 + vc + c2);
    }
    float q[64];
    {
        const uint4* qp = (const uint4*)(qkv + rowBase + (size_t)t * 3072 + h * 64);
        #pragma unroll
        for (int i = 0; i < 8; i++) {
            uint4 u = qp[i];
            q[i*8+0] = bflo(u.x); q[i*8+1] = bfhi(u.x);
            q[i*8+2] = bflo(u.y); q[i*8+3] = bfhi(u.y);
            q[i*8+4] = bflo(u.z); q[i*8+5] = bfhi(u.z);
            q[i*8+6] = bflo(u.w); q[i*8+7] = bfhi(u.w);
        }
    }
    __syncthreads();
    float acc[64];
    #pragma unroll
    for (int d = 0; d < 64; d++) acc[d] = 0.f;
    float den = 0.f;
    for (int j = 0; j < 256; j++) {
        const uint4* kp = (const uint4*)&Ks[j * 32];
        float s = 0.f;
        #pragma unroll
        for (int i = 0; i < 8; i++) {
            uint4 u = kp[i];
            s += bflo(u.x)*q[i*8+0] + bfhi(u.x)*q[i*8+1]
               + bflo(u.y)*q[i*8+2] + bfhi(u.y)*q[i*8+3]
               + bflo(u.z)*q[i*8+4] + bfhi(u.z)*q[i*8+5]
               + bflo(u.w)*q[i*8+6] + bfhi(u.w)*q[i*8+7];
        }
        float p = __expf(s * 0.125f);
        den += p;
        const uint4* vp = (const uint4*)&Vs[j * 32];
        #pragma unroll
        for (int i = 0; i < 8; i++) {
            uint4 u = vp[i];
            acc[i*8+0] += p * bflo(u.x); acc[i*8+1] += p * bfhi(u.x);
            acc[i*8+2] += p * bflo(u.y); acc[i*8+3] += p * bfhi(u.y);
            acc[i*8+4] += p * bflo(u.z); acc[i*8+5] += p * bfhi(u.z);
            acc[i*8+6] += p * bflo(u.w); acc[i*8+7] += p * bfhi(u.w);
        }
    }
    const float inv = 1.f / den;
    u16* op = att + ((size_t)e * MTOK + (size_t)b * NS + t) * NU + h * 64;
    #pragma unroll
    for (int i = 0; i < 32; i++)
        ((u32*)op)[i] = pack2(acc[2*i] * inv, acc[2*i+1] * inv);
}

// ---------------- persistent LSTM ----------------
// 256 WGs co-resident. WG owns 16 hidden units of one expert; whh slice in registers.
// NO acquire/release, NO flags: h published as tagged u64 words ((tag|h1)<<32 | (tag|h0)),
// relaxed agent-scope atomics only (sc-bypass to LLC; no buffer_inv / buffer_wbl2 storms).
// Consumers poll the data words themselves until all carry the current step's tag.
// Ping-pong parity + tag disambiguates reuse (a WG reaches overwrite of parity p only
// after every WG published the intervening step).
__global__ __launch_bounds__(256, 1) void lstm_kernel(
    const float* __restrict__ whh, const u16* __restrict__ xz,
    u64* __restrict__ hbuf,        // [2][E][64 wg][64] u64 tagged unit-pairs
    u16* __restrict__ mbuf)        // [E][MTOK][NU]
{
    const int wg = blockIdx.x;
    const int e = wg >> 6;
    const int w63 = wg & 63;
    const int j0 = w63 * 16;
    const int t = threadIdx.x;
    const int g = t >> 6, lane = t & 63;
    const int quad = lane >> 4, l16 = lane & 15;

    __shared__ u16  hsh[16][1032];      // h staged bf16 [batch][unit], rows 8..15 unused pad
    __shared__ float zbuf[4][16][8];    // [gate][unit][batch]

    for (int i = t; i < 16 * 1032; i += 256) (&hsh[0][0])[i] = 0;

    // preload B-fragments: B[k][n] = whh[n][k]; lane n=l16, k=quad*8+j
    bfrag wf[32];
    const float* wrow = whh + ((size_t)e * 4096 + (size_t)g * 1024 + j0 + l16) * 1024 + quad * 8;
    #pragma unroll
    for (int kk = 0; kk < 32; kk++) {
        const float* p = wrow + kk * 32;
        float4 f0 = *(const float4*)p;
        float4 f1 = *(const float4*)(p + 4);
        union { u16 s[8]; bfrag v; } uu;
        uu.s[0]=f2bf(f0.x); uu.s[1]=f2bf(f0.y); uu.s[2]=f2bf(f0.z); uu.s[3]=f2bf(f0.w);
        uu.s[4]=f2bf(f1.x); uu.s[5]=f2bf(f1.y); uu.s[6]=f2bf(f1.z); uu.s[7]=f2bf(f1.w);
        wf[kk] = uu.v;
    }
    __syncthreads();

    float c0 = 0.f, c1 = 0.f;          // fp32 cell state in wave-0 registers
    const int bb = t & 7, u0 = ((t >> 3) & 7) * 2;

    for (int st = 0; st < NS; st++) {
        // xz loads for this step issued FIRST (latency hidden behind the poll)
        u32 zi, zf, zgv, zo;
        if (t < 64) {
            const u16* xp = xz + (((size_t)e * NS + st) * NB + bb) * 4096 + j0 + u0;
            zi  = *(const u32*)(xp);
            zf  = *(const u32*)(xp + 1024);
            zgv = *(const u32*)(xp + 2048);
            zo  = *(const u32*)(xp + 3072);
        }
        // poll tagged h words for step st (tag==st; memset zeros give tag 0 == h_0 == 0)
        {
            u64* hsrc = hbuf + ((size_t)(st & 1) * NE + e) * 4096;
            const u32 tagw = (u32)st;
            u32 pend = 0xFFFFu;
            while (pend) {
                u32 np = 0;
                #pragma unroll
                for (int i = 0; i < 16; i++) {
                    if ((pend >> i) & 1u) {
                        int idx = t + i * 256;
                        u64 v = __hip_atomic_load(hsrc + idx, __ATOMIC_RELAXED,
                                                  __HIP_MEMORY_SCOPE_AGENT);
                        if ((u32)((v >> 16) & 0xFFFF) == tagw && (u32)(v >> 48) == tagw) {
                            int sw = idx >> 6, sjp = (idx >> 3) & 7, sbb = idx & 7;
                            *(u32*)&hsh[sbb][sw * 16 + sjp * 2] =
                                (u32)(v & 0xFFFF) | ((u32)((v >> 32) & 0xFFFF) << 16);
                        } else np |= 1u << i;
                    }
                }
                pend = np;
                if (pend) __builtin_amdgcn_s_sleep(1);
            }
        }
        __syncthreads();
        // zg partial = h @ whh_slice^T; 4 independent MFMA chains (latency off critical path)
        f32x4 ac0 = {}, ac1 = {}, ac2 = {}, ac3 = {};
        #pragma unroll
        for (int kk = 0; kk < 8; kk++) {
            ac0 = __builtin_amdgcn_mfma_f32_16x16x32_bf16(*(const bfrag*)&hsh[l16][(kk     ) * 32 + quad * 8], wf[kk     ], ac0, 0, 0, 0);
            ac1 = __builtin_amdgcn_mfma_f32_16x16x32_bf16(*(const bfrag*)&hsh[l16][(kk +  8) * 32 + quad * 8], wf[kk +  8], ac1, 0, 0, 0);
            ac2 = __builtin_amdgcn_mfma_f32_16x16x32_bf16(*(const bfrag*)&hsh[l16][(kk + 16) * 32 + quad * 8], wf[kk + 16], ac2, 0, 0, 0);
            ac3 = __builtin_amdgcn_mfma_f32_16x16x32_bf16(*(const bfrag*)&hsh[l16][(kk + 24) * 32 + quad * 8], wf[kk + 24], ac3, 0, 0, 0);
        }
        f32x4 acc = (ac0 + ac1) + (ac2 + ac3);
        #pragma unroll
        for (int r = 0; r < 4; r++) {
            int rb = quad * 4 + r;
            if (rb < 8) zbuf[g][l16][rb] = acc[r];   // col=lane&15(unit), row=quad*4+r(batch)
        }
        __syncthreads();
        // gate math: 64 threads (wave 0), each one (unit-pair, batch)
        if (t < 64) {
            float i0 = zbuf[0][u0][bb]   + bflo(zi);
            float i1 = zbuf[0][u0+1][bb] + bfhi(zi);
            float f0 = zbuf[1][u0][bb]   + bflo(zf);
            float f1 = zbuf[1][u0+1][bb] + bfhi(zf);
            float g0 = zbuf[2][u0][bb]   + bflo(zgv);
            float g1 = zbuf[2][u0+1][bb] + bfhi(zgv);
            float o0 = zbuf[3][u0][bb]   + bflo(zo);
            float o1 = zbuf[3][u0+1][bb] + bfhi(zo);
            c0 = sigm(f0) * c0 + sigm(i0) * tanhf(g0);
            c1 = sigm(f1) * c1 + sigm(i1) * tanhf(g1);
            float h0 = sigm(o0) * tanhf(c0);
            float h1 = sigm(o1) * tanhf(c1);
            // hs output, token-major [e][b*256+st][u]
            *(u32*)(mbuf + (((size_t)e * NB + bb) * NS + st) * NU + j0 + u0) = pack2(h0, h1);
            if (st < NS - 1) {
                const u32 tag = (u32)(st + 1) << 16;
                u64 v = ((u64)(tag | (u32)f2bf(h1)) << 32) | (u64)(tag | (u32)f2bf(h0));
                u64* hdst = hbuf + ((size_t)((st + 1) & 1) * NE + e) * 4096 + w63 * 64 + t;
                __hip_atomic_store(hdst, v, __ATOMIC_RELAXED, __HIP_MEMORY_SCOPE_AGENT);
            }
        }
        __syncthreads();
    }
}

// ---------------- final: per-expert LN + gate-weighted combine -> fp32 out ----------------
__global__ __launch_bounds__(256) void final_kernel(const u16* __restrict__ dec2,
                                                    const float* __restrict__ gam,
                                                    const float* __restrict__ bet,
                                                    const float* __restrict__ gates,
                                                    float* __restrict__ outp) {
    const int row = blockIdx.x;        // b*256+s
    const int b = row >> 8;
    const int t = threadIdx.x;
    const int wave = t >> 6, lane = t & 63;
    __shared__ float rb[4][2];
    float o0 = 0.f, o1 = 0.f, o2 = 0.f, o3 = 0.f;
    for (int e = 0; e < NE; e++) {
        uint2 u = *(const uint2*)(dec2 + ((size_t)e * MTOK + row) * ND + t * 4);
        float v0 = bflo(u.x), v1 = bfhi(u.x), v2 = bflo(u.y), v3 = bfhi(u.y);
        float s1 = v0 + v1 + v2 + v3;
        float s2 = v0*v0 + v1*v1 + v2*v2 + v3*v3;
        for (int o = 32; o; o >>= 1) { s1 += __shfl_down(s1, o); s2 += __shfl_down(s2, o); }
        __syncthreads();
        if (lane == 0) { rb[wave][0] = s1; rb[wave][1] = s2; }
        __syncthreads();
        s1 = rb[0][0] + rb[1][0] + rb[2][0] + rb[3][0];
        s2 = rb[0][1] + rb[1][1] + rb[2][1] + rb[3][1];
        const float mu = s1 * (1.f / ND);
        const float rstd = rsqrtf(s2 * (1.f / ND) - mu * mu + 1e-5f);
        const float ge = gates[b * NE + e];
        const float* gp = gam + e * ND + t * 4;
        const float* bp = bet + e * ND + t * 4;
        o0 += ge * ((v0 - mu) * rstd * gp[0] + bp[0]);
        o1 += ge * ((v1 - mu) * rstd * gp[1] + bp[1]);
        o2 += ge * ((v2 - mu) * rstd * gp[2] + bp[2]);
        o3 += ge * ((v3 - mu) * rstd * gp[3] + bp[3]);
    }
    float4 r; r.x = o0; r.y = o1; r.z = o2; r.w = o3;
    *(float4*)(outp + (size_t)row * ND + t * 4) = r;
}

// ---------------- workspace layout (bytes) ----------------
constexpr size_t OFF_WBUF  = 0;                       // 32MB: bf16 copy of current weight (max: wih)
constexpr size_t OFF_XBF   = 33554432;                // 4MB : x bf16
constexpr size_t OFF_A     = 37748736;                // 16MB: t1 / att / u1 / d1
constexpr size_t OFF_B     = 54525952;                // 16MB: t2 / att2 / o1
constexpr size_t OFF_HM    = 71303168;                // 16MB: h (enc LN out) then m (LSTM out)
constexpr size_t OFF_QX    = 88080384;                // 64MB: qkv then xz
constexpr size_t OFF_C     = 155189248;               // 16MB: u_ then dec2
constexpr size_t OFF_D     = 171966464;               // 16MB: gt; ALSO hosts LSTM hbuf (256KB)
                                                      //   (hbuf dead before gemm<3> writes gt)
constexpr size_t OFF_XM    = 188743680;               // 32KB: pooled x
constexpr size_t OFF_GATES = 188776448;               // gates (pad 256)

extern "C" void kernel_launch(void* const* d_in, const int* in_sizes, int n_in,
                              void* d_out, int out_size, void* d_ws, size_t ws_size,
                              hipStream_t stream) {
    const float* x        = (const float*)d_in[0];
    const float* router_w = (const float*)d_in[1];
    const float* router_b = (const float*)d_in[2];
    const float* enc_w1   = (const float*)d_in[3];
    const float* enc_b1   = (const float*)d_in[4];
    const float* enc_w2   = (const float*)d_in[5];
    const float* enc_b2   = (const float*)d_in[6];
    const float* enc_ln_g = (const float*)d_in[7];
    const float* enc_ln_b = (const float*)d_in[8];
    const float* wqkv     = (const float*)d_in[9];
    const float* bqkv     = (const float*)d_in[10];
    const float* wo       = (const float*)d_in[11];
    const float* bo       = (const float*)d_in[12];
    const float* wih      = (const float*)d_in[13];
    const float* whh      = (const float*)d_in[14];
    const float* bih      = (const float*)d_in[15];
    const float* bhh      = (const float*)d_in[16];
    const float* uw1      = (const float*)d_in[17];
    const float* ub1      = (const float*)d_in[18];
    const float* uw2      = (const float*)d_in[19];
    const float* ub2      = (const float*)d_in[20];
    const float* ow1      = (const float*)d_in[21];
    const float* ob1      = (const float*)d_in[22];
    const float* ow2      = (const float*)d_in[23];
    const float* ob2      = (const float*)d_in[24];
    const float* dw1      = (const float*)d_in[25];
    const float* db1      = (const float*)d_in[26];
    const float* dw2      = (const float*)d_in[27];
    const float* db2      = (const float*)d_in[28];
    const float* dec_ln_g = (const float*)d_in[29];
    const float* dec_ln_b = (const float*)d_in[30];

    char* W = (char*)d_ws;
    u16* wbuf   = (u16*)(W + OFF_WBUF);
    u16* x_bf   = (u16*)(W + OFF_XBF);
    u16* bufA   = (u16*)(W + OFF_A);
    u16* bufB   = (u16*)(W + OFF_B);
    u16* hm     = (u16*)(W + OFF_HM);
    u16* qx     = (u16*)(W + OFF_QX);
    u16* bufC   = (u16*)(W + OFF_C);
    u16* bufD   = (u16*)(W + OFF_D);
    float* xm   = (float*)(W + OFF_XM);
    float* gate = (float*)(W + OFF_GATES);
    u64* hbuf   = (u64*)(W + OFF_D);      // 256KB, lives only during lstm (before gt written)

    // zero LSTM tagged-h ping-pong (tag 0 == initial h == 0); ws is poisoned 0xAA each call
    hipMemsetAsync(W + OFF_D, 0, 262144, stream);

    const int nW1  = NE * NU * ND;      // 4M elems (1024x1024 weights)
    const int gW1  = nW1 / 2048;
    dim3 blk(256);

    // x -> bf16 ; router
    cvt_f32_bf16<<<MTOK * ND / 2048, blk, 0, stream>>>(x, x_bf, MTOK * ND);
    pool_kernel<<<32, blk, 0, stream>>>(x, xm);
    gates_kernel<<<NB, blk, 0, stream>>>(xm, router_w, router_b, gate);

    // encoder
    cvt_f32_bf16<<<gW1, blk, 0, stream>>>(enc_w1, wbuf, nW1);
    gemm_bt<1><<<dim3(8, 16, NE), blk, 0, stream>>>(x_bf, 0, wbuf, enc_b1, nullptr, nullptr, bufA, 1024, 1024);
    cvt_f32_bf16<<<gW1, blk, 0, stream>>>(enc_w2, wbuf, nW1);
    gemm_bt<0><<<dim3(8, 16, NE), blk, 0, stream>>>(bufA, 1, wbuf, enc_b2, nullptr, nullptr, bufB, 1024, 1024);
    ln_kernel<<<NE * MTOK, blk, 0, stream>>>(bufB, enc_ln_g, enc_ln_b, hm);

    // attention
    cvt_f32_bf16<<<3 * gW1, blk, 0, stream>>>(wqkv, wbuf, 3 * nW1);
    gemm_bt<0><<<dim3(24, 16, NE), blk, 0, stream>>>(hm, 1, wbuf, bqkv, nullptr, nullptr, qx, 3072, 1024);
    attn_kernel<<<NE * NB * 16, blk, 0, stream>>>(qx, bufA);
    cvt_f32_bf16<<<gW1, blk, 0, stream>>>(wo, wbuf, nW1);
    gemm_bt<0><<<dim3(8, 16, NE), blk, 0, stream>>>(bufA, 1, wbuf, bo, nullptr, nullptr, bufB, 1024, 1024);

    // LSTM input xz = att2 @ wih^T + bih + bhh, layout [e][s][b][4096]
    cvt_f32_bf16<<<4 * gW1, blk, 0, stream>>>(wih, wbuf, 4 * nW1);
    gemm_bt<4><<<dim3(32, 16, NE), blk, 0, stream>>>(bufB, 1, wbuf, bih, bhh, nullptr, qx, 4096, 1024);
    lstm_kernel<<<256, blk, 0, stream>>>(whh, qx, hbuf, hm);

    // understanding (sigmoid) & optimization (tanh) branches, gated product
    cvt_f32_bf16<<<gW1, blk, 0, stream>>>(uw1, wbuf, nW1);
    gemm_bt<1><<<dim3(8, 16, NE), blk, 0, stream>>>(hm, 1, wbuf, ub1, nullptr, nullptr, bufA, 1024, 1024);
    cvt_f32_bf16<<<gW1, blk, 0, stream>>>(uw2, wbuf, nW1);
    gemm_bt<2><<<dim3(8, 16, NE), blk, 0, stream>>>(bufA, 1, wbuf, ub2, nullptr, nullptr, bufC, 1024, 1024);
    cvt_f32_bf16<<<gW1, blk, 0, stream>>>(ow1, wbuf, nW1);
    gemm_bt<1><<<dim3(8, 16, NE), blk, 0, stream>>>(hm, 1, wbuf, ob1, nullptr, nullptr, bufB, 1024, 1024);
    cvt_f32_bf16<<<gW1, blk, 0, stream>>>(ow2, wbuf, nW1);
    gemm_bt<3><<<dim3(8, 16, NE), blk, 0, stream>>>(bufB, 1, wbuf, ob2, nullptr, bufC, bufD, 1024, 1024);

    // decoder
    cvt_f32_bf16<<<gW1, blk, 0, stream>>>(dw1, wbuf, nW1);
    gemm_bt<1><<<dim3(8, 16, NE), blk, 0, stream>>>(bufD, 1, wbuf, db1, nullptr, nullptr, bufA, 1024, 1024);
    cvt_f32_bf16<<<gW1, blk, 0, stream>>>(dw2, wbuf, nW1);
    gemm_bt<0><<<dim3(8, 16, NE), blk, 0, stream>>>(bufA, 1, wbuf, db2, nullptr, nullptr, bufC, 1024, 1024);

    // final LN + routed combine
    final_kernel<<<MTOK, blk, 0, stream>>>(bufC, dec_ln_g, dec_ln_b, gate, (float*)d_out);
}